// Round 3
// baseline (184.144 us; speedup 1.0000x reference)
//
#include <hip/hip_runtime.h>
#include <stdint.h>

#define D     512
#define NSUP  5000   // 1000 classes * 5 shots
#define NQRY  5000
#define NPAD  5120   // 40 tiles of 128
#define MEAN_BLOCKS 100
#define ROWS_PER_MEAN_BLOCK 50
#define SCALE 512.0f

// ---------------- ws layout (bytes) ----------------
// shi  : [5120][512] f16 @ 0          (5,242,880)
// slo  : [5120][512] f16 @ 5,242,880
// qhi  : [5120][512] f16 @ 10,485,760
// qlo  : [5120][512] f16 @ 15,728,640
// partial : [100][512] f32 @ 20,971,520 (204,800)
// mean    : [512] f32      @ 21,176,320 (2,048)
// keys    : [5000] u64     @ 21,178,368 (40,000)   -> total 21,218,368 (unchanged)
#define OFF_SHI     0
#define OFF_SLO     5242880
#define OFF_QHI     10485760
#define OFF_QLO     15728640
#define OFF_PARTIAL 20971520
#define OFF_MEAN    21176320
#define OFF_KEYS    21178368

typedef _Float16 half4v __attribute__((ext_vector_type(4)));
typedef _Float16 half8v __attribute__((ext_vector_type(8)));
typedef float    f32x4  __attribute__((ext_vector_type(4)));

__device__ __forceinline__ unsigned long long pack_key(float v, int sidx) {
    unsigned u = __float_as_uint(v);
    u = (u & 0x80000000u) ? ~u : (u | 0x80000000u);   // monotone float->uint
    return ((unsigned long long)u << 32) | (unsigned)(0xFFFFFFFFu - (unsigned)sidx);
}

__device__ __forceinline__ void gload16(const void* g, void* l) {
    __builtin_amdgcn_global_load_lds(
        (const __attribute__((address_space(1))) unsigned int*)g,
        (__attribute__((address_space(3))) unsigned int*)l, 16, 0, 0);
}

// K1: partial column sums of support rows (deterministic 2-stage mean)
__global__ void k_partial_mean(const float* __restrict__ sup, float* __restrict__ partial) {
    const int col = threadIdx.x;           // 512
    const int b   = blockIdx.x;            // 100
    const int r0  = b * ROWS_PER_MEAN_BLOCK;
    float acc = 0.0f;
    #pragma unroll 5
    for (int r = 0; r < ROWS_PER_MEAN_BLOCK; ++r)
        acc += sup[(size_t)(r0 + r) * D + col];
    partial[b * D + col] = acc;
}

// K2: finish mean, zero keys
__global__ void k_mean_init(const float* __restrict__ partial, float* __restrict__ mean,
                            unsigned long long* __restrict__ keys) {
    const int col = threadIdx.x;           // 512
    float acc = 0.0f;
    #pragma unroll 4
    for (int b = 0; b < MEAN_BLOCKS; ++b) acc += partial[b * D + col];
    mean[col] = acc * (1.0f / (float)NSUP);
    for (int i = col; i < NSUP; i += 512) keys[i] = 0ull;
}

// K3: center + L2-normalize + scale by 512 + split into fp16 hi/lo.
// 512 threads = 4 rows x 128 threads; pad rows written as zeros.
__global__ void k_split(const float* __restrict__ sup, const float* __restrict__ qry,
                        const float* __restrict__ mean,
                        _Float16* __restrict__ shi, _Float16* __restrict__ slo,
                        _Float16* __restrict__ qhi, _Float16* __restrict__ qlo) {
    const int t    = threadIdx.x;
    const int rloc = t >> 7;               // row within block, 0..3
    const int tc   = t & 127;              // 128 threads per row
    const int b    = (int)blockIdx.x * 4 + rloc;   // global row id 0..10239
    const float* src; _Float16 *dhi, *dlo; int valid;
    if (b < NPAD) { src = sup + (size_t)b * D;
                    dhi = shi + (size_t)b * D; dlo = slo + (size_t)b * D; valid = (b < NSUP); }
    else          { int r = b - NPAD; src = qry + (size_t)r * D;
                    dhi = qhi + (size_t)r * D; dlo = qlo + (size_t)r * D; valid = (r < NQRY); }
    __shared__ float red[8];
    if (!valid) {
        half4v z = {};
        *(half4v*)(dhi + tc * 4) = z;
        *(half4v*)(dlo + tc * 4) = z;
        return;
    }
    float4 v = *(const float4*)(src + tc * 4);
    float4 m = *(const float4*)(mean + tc * 4);
    v.x -= m.x; v.y -= m.y; v.z -= m.z; v.w -= m.w;
    float ss = v.x * v.x + v.y * v.y + v.z * v.z + v.w * v.w;
    #pragma unroll
    for (int off = 32; off > 0; off >>= 1) ss += __shfl_down(ss, off, 64);
    if ((t & 63) == 0) red[t >> 6] = ss;
    __syncthreads();
    const float rn = SCALE / sqrtf(red[rloc * 2] + red[rloc * 2 + 1]);
    float sv[4] = {v.x * rn, v.y * rn, v.z * rn, v.w * rn};
    half4v h, l;
    #pragma unroll
    for (int i = 0; i < 4; ++i) {
        _Float16 hh = (_Float16)sv[i];
        h[i] = hh;
        l[i] = (_Float16)(sv[i] - (float)hh);
    }
    *(half4v*)(dhi + tc * 4) = h;
    *(half4v*)(dlo + tc * 4) = l;
}

// K4: MFMA sim-GEMM (3-term fp16-split), double-buffered LDS, 1 barrier/half-step.
// 128x128 tile, BK=32, 256 threads, wave tile 64x64 (4x4 frags of 16x16x32).
__launch_bounds__(256)
__global__ void k_main(const _Float16* __restrict__ shi, const _Float16* __restrict__ slo,
                       const _Float16* __restrict__ qhi, const _Float16* __restrict__ qlo,
                       unsigned long long* __restrict__ keys) {
    __shared__ __align__(16) _Float16 lds_shi[2 * 4096];
    __shared__ __align__(16) _Float16 lds_slo[2 * 4096];
    __shared__ __align__(16) _Float16 lds_qhi[2 * 4096];
    __shared__ __align__(16) _Float16 lds_qlo[2 * 4096];
    __shared__ unsigned long long kl[128];

    const int tid  = threadIdx.x;
    const int lane = tid & 63;
    const int wv   = tid >> 6;            // 4 waves
    const int q0   = blockIdx.x * 128;
    const int s0   = blockIdx.y * 128;

    // ---- staging addresses (swizzle: slot ^= (row>>1)&3, 16B slots) ----
    const int m0  = wv * 32 + (lane >> 2);       // row for chunk 0
    const int m1  = m0 + 16;                     // row for chunk 1
    const int sl0 = ((lane & 3) ^ ((m0 >> 1) & 3)) * 16;
    const int sl1 = ((lane & 3) ^ ((m1 >> 1) & 3)) * 16;
    const char* pShi = (const char*)shi; const char* pSlo = (const char*)slo;
    const char* pQhi = (const char*)qhi; const char* pQlo = (const char*)qlo;
    const size_t rS0 = (size_t)(s0 + m0) * 1024 + sl0;
    const size_t rS1 = (size_t)(s0 + m1) * 1024 + sl1;
    const size_t rQ0 = (size_t)(q0 + m0) * 1024 + sl0;
    const size_t rQ1 = (size_t)(q0 + m1) * 1024 + sl1;
    _Float16* d_shi0 = lds_shi + wv * 1024;      _Float16* d_shi1 = lds_shi + wv * 1024 + 512;
    _Float16* d_slo0 = lds_slo + wv * 1024;      _Float16* d_slo1 = lds_slo + wv * 1024 + 512;
    _Float16* d_qhi0 = lds_qhi + wv * 1024;      _Float16* d_qhi1 = lds_qhi + wv * 1024 + 512;
    _Float16* d_qlo0 = lds_qlo + wv * 1024;      _Float16* d_qlo1 = lds_qlo + wv * 1024 + 512;

    // ---- fragment read addresses (same swizzle) ----
    const int l15 = lane & 15;
    const int kg  = lane >> 4;                   // k-group 0..3
    const int fo  = l15 * 64 + ((kg ^ ((l15 >> 1) & 3)) * 16);
    const int sm  = (wv & 1) * 64;               // support row base in tile
    const int qm  = (wv >> 1) * 64;              // query row base in tile
    const char* fShi = (const char*)lds_shi + (size_t)sm * 64 + fo;
    const char* fSlo = (const char*)lds_slo + (size_t)sm * 64 + fo;
    const char* fQhi = (const char*)lds_qhi + (size_t)qm * 64 + fo;
    const char* fQlo = (const char*)lds_qlo + (size_t)qm * 64 + fo;

    f32x4 acc[4][4] = {};
    if (tid < 128) kl[tid] = 0ull;

#define STAGE(B, KC) do {                                                          \
        const size_t kb_ = (size_t)(KC) * 2;                                       \
        gload16(pShi + rS0 + kb_, d_shi0 + (B) * 4096);                            \
        gload16(pShi + rS1 + kb_, d_shi1 + (B) * 4096);                            \
        gload16(pSlo + rS0 + kb_, d_slo0 + (B) * 4096);                            \
        gload16(pSlo + rS1 + kb_, d_slo1 + (B) * 4096);                            \
        gload16(pQhi + rQ0 + kb_, d_qhi0 + (B) * 4096);                            \
        gload16(pQhi + rQ1 + kb_, d_qhi1 + (B) * 4096);                            \
        gload16(pQlo + rQ0 + kb_, d_qlo0 + (B) * 4096);                            \
        gload16(pQlo + rQ1 + kb_, d_qlo1 + (B) * 4096);                            \
    } while (0)

#define COMPUTE(B) do {                                                            \
        half8v ah[4], al[4], bh[4], bl[4];                                         \
        _Pragma("unroll")                                                          \
        for (int f = 0; f < 4; ++f) {                                              \
            ah[f] = *(const half8v*)(fShi + (B) * 8192 + f * 1024);                \
            al[f] = *(const half8v*)(fSlo + (B) * 8192 + f * 1024);                \
            bh[f] = *(const half8v*)(fQhi + (B) * 8192 + f * 1024);                \
            bl[f] = *(const half8v*)(fQlo + (B) * 8192 + f * 1024);                \
        }                                                                          \
        _Pragma("unroll")                                                          \
        for (int fa = 0; fa < 4; ++fa)                                             \
            _Pragma("unroll")                                                      \
            for (int fb = 0; fb < 4; ++fb) {                                       \
                acc[fa][fb] = __builtin_amdgcn_mfma_f32_16x16x32_f16(ah[fa], bh[fb], acc[fa][fb], 0, 0, 0); \
                acc[fa][fb] = __builtin_amdgcn_mfma_f32_16x16x32_f16(ah[fa], bl[fb], acc[fa][fb], 0, 0, 0); \
                acc[fa][fb] = __builtin_amdgcn_mfma_f32_16x16x32_f16(al[fa], bh[fb], acc[fa][fb], 0, 0, 0); \
            }                                                                      \
    } while (0)

    // prologue: fill buffer 0 with K-chunk 0
    STAGE(0, 0);
    __syncthreads();                 // compiler drains vmcnt before barrier

    // 8 double-steps cover D=512 (2 x BK=32 per step); STAGE(next) issued
    // BEFORE compute so loads overlap the MFMA phase, drained by the barrier.
    for (int i = 0; i < 8; ++i) {
        const int kc = i * 64;
        STAGE(1, kc + 32);
        COMPUTE(0);
        __syncthreads();
        if (i < 7) STAGE(0, kc + 64);
        COMPUTE(1);
        __syncthreads();
    }
#undef STAGE
#undef COMPUTE

    // ---- fused argmax epilogue ----
    // C/D: col(query) = lane&15 (+fb*16+qm), row(support) = kg*4 + r (+fa*16+sm)
    #pragma unroll
    for (int fb = 0; fb < 4; ++fb) {
        unsigned long long best = 0ull;
        #pragma unroll
        for (int fa = 0; fa < 4; ++fa)
            #pragma unroll
            for (int r = 0; r < 4; ++r) {
                const int s = s0 + sm + fa * 16 + kg * 4 + r;
                if (s < NSUP) {
                    unsigned long long k = pack_key(acc[fa][fb][r], s);
                    if (k > best) best = k;
                }
            }
        unsigned long long o = __shfl_xor(best, 16, 64); if (o > best) best = o;
        o = __shfl_xor(best, 32, 64);                    if (o > best) best = o;
        if (kg == 0) atomicMax(&kl[qm + fb * 16 + l15], best);
    }
    __syncthreads();
    if (tid < 128) {
        const int q = q0 + tid;
        if (q < NQRY && kl[tid] != 0ull) atomicMax(&keys[q], kl[tid]);
    }
}

// K5: decode packed key -> class index
__global__ void k_decode(const unsigned long long* __restrict__ keys, int* __restrict__ out) {
    const int q = blockIdx.x * 256 + threadIdx.x;
    if (q < NQRY) {
        unsigned sidx = 0xFFFFFFFFu - (unsigned)(keys[q] & 0xFFFFFFFFull);
        out[q] = (int)(sidx / 5u);
    }
}

extern "C" void kernel_launch(void* const* d_in, const int* in_sizes, int n_in,
                              void* d_out, int out_size, void* d_ws, size_t ws_size,
                              hipStream_t stream) {
    const float* sup = (const float*)d_in[0];   // [1000,5,512]
    const float* qry = (const float*)d_in[1];   // [5000,512]
    // d_in[2] = use_cosine: after normalization argmin-euclid == argmax-cosine.
    int* out = (int*)d_out;

    char* ws = (char*)d_ws;
    _Float16* shi = (_Float16*)(ws + OFF_SHI);
    _Float16* slo = (_Float16*)(ws + OFF_SLO);
    _Float16* qhi = (_Float16*)(ws + OFF_QHI);
    _Float16* qlo = (_Float16*)(ws + OFF_QLO);
    float* partial = (float*)(ws + OFF_PARTIAL);
    float* mean    = (float*)(ws + OFF_MEAN);
    unsigned long long* keys = (unsigned long long*)(ws + OFF_KEYS);

    k_partial_mean<<<MEAN_BLOCKS, 512, 0, stream>>>(sup, partial);
    k_mean_init<<<1, 512, 0, stream>>>(partial, mean, keys);
    k_split<<<(2 * NPAD) / 4, 512, 0, stream>>>(sup, qry, mean, shi, slo, qhi, qlo);
    dim3 grid(NPAD / 128, NPAD / 128);
    k_main<<<grid, 256, 0, stream>>>(shi, slo, qhi, qlo, keys);
    k_decode<<<(NQRY + 255) / 256, 256, 0, stream>>>(keys, out);
}

// Round 4
// 174.744 us; speedup vs baseline: 1.0538x; 1.0538x over previous
//
#include <hip/hip_runtime.h>
#include <stdint.h>

#define D     512
#define NSUP  5000   // 1000 classes * 5 shots
#define NQRY  5000
#define NPAD  5120   // 20 tiles of 256
#define MEAN_BLOCKS 100
#define ROWS_PER_MEAN_BLOCK 50
#define SCALE 512.0f

// ---------------- ws layout (bytes, unchanged) ----------------
#define OFF_SHI     0
#define OFF_SLO     5242880
#define OFF_QHI     10485760
#define OFF_QLO     15728640
#define OFF_PARTIAL 20971520
#define OFF_MEAN    21176320
#define OFF_KEYS    21178368

// ---------------- dynamic LDS layout (bytes) ----------------
// 4 arrays x [2 bufs][256 rows][64B] = 4 x 32768, then kl[256] u64
#define SH_SHI   0
#define SH_SLO   32768
#define SH_QHI   65536
#define SH_QLO   98304
#define SH_KL    131072
#define SH_TOTAL (131072 + 2048)

typedef _Float16 half4v __attribute__((ext_vector_type(4)));
typedef _Float16 half8v __attribute__((ext_vector_type(8)));
typedef float    f32x4  __attribute__((ext_vector_type(4)));

__device__ __forceinline__ unsigned long long pack_key(float v, int sidx) {
    unsigned u = __float_as_uint(v);
    u = (u & 0x80000000u) ? ~u : (u | 0x80000000u);   // monotone float->uint
    return ((unsigned long long)u << 32) | (unsigned)(0xFFFFFFFFu - (unsigned)sidx);
}

__device__ __forceinline__ void gload16(const void* g, void* l) {
    __builtin_amdgcn_global_load_lds(
        (const __attribute__((address_space(1))) unsigned int*)g,
        (__attribute__((address_space(3))) unsigned int*)l, 16, 0, 0);
}

// K1: partial column sums of support rows (deterministic 2-stage mean)
__global__ void k_partial_mean(const float* __restrict__ sup, float* __restrict__ partial) {
    const int col = threadIdx.x;           // 512
    const int b   = blockIdx.x;            // 100
    const int r0  = b * ROWS_PER_MEAN_BLOCK;
    float acc = 0.0f;
    #pragma unroll 5
    for (int r = 0; r < ROWS_PER_MEAN_BLOCK; ++r)
        acc += sup[(size_t)(r0 + r) * D + col];
    partial[b * D + col] = acc;
}

// K2: finish mean, zero keys
__global__ void k_mean_init(const float* __restrict__ partial, float* __restrict__ mean,
                            unsigned long long* __restrict__ keys) {
    const int col = threadIdx.x;           // 512
    float acc = 0.0f;
    #pragma unroll 4
    for (int b = 0; b < MEAN_BLOCKS; ++b) acc += partial[b * D + col];
    mean[col] = acc * (1.0f / (float)NSUP);
    for (int i = col; i < NSUP; i += 512) keys[i] = 0ull;
}

// K3: center + L2-normalize + scale by 512 + split into fp16 hi/lo.
__global__ void k_split(const float* __restrict__ sup, const float* __restrict__ qry,
                        const float* __restrict__ mean,
                        _Float16* __restrict__ shi, _Float16* __restrict__ slo,
                        _Float16* __restrict__ qhi, _Float16* __restrict__ qlo) {
    const int t    = threadIdx.x;
    const int rloc = t >> 7;               // row within block, 0..3
    const int tc   = t & 127;              // 128 threads per row
    const int b    = (int)blockIdx.x * 4 + rloc;   // global row id 0..10239
    const float* src; _Float16 *dhi, *dlo; int valid;
    if (b < NPAD) { src = sup + (size_t)b * D;
                    dhi = shi + (size_t)b * D; dlo = slo + (size_t)b * D; valid = (b < NSUP); }
    else          { int r = b - NPAD; src = qry + (size_t)r * D;
                    dhi = qhi + (size_t)r * D; dlo = qlo + (size_t)r * D; valid = (r < NQRY); }
    __shared__ float red[8];
    if (!valid) {
        half4v z = {};
        *(half4v*)(dhi + tc * 4) = z;
        *(half4v*)(dlo + tc * 4) = z;
        return;
    }
    float4 v = *(const float4*)(src + tc * 4);
    float4 m = *(const float4*)(mean + tc * 4);
    v.x -= m.x; v.y -= m.y; v.z -= m.z; v.w -= m.w;
    float ss = v.x * v.x + v.y * v.y + v.z * v.z + v.w * v.w;
    #pragma unroll
    for (int off = 32; off > 0; off >>= 1) ss += __shfl_down(ss, off, 64);
    if ((t & 63) == 0) red[t >> 6] = ss;
    __syncthreads();
    const float rn = SCALE / sqrtf(red[rloc * 2] + red[rloc * 2 + 1]);
    float sv[4] = {v.x * rn, v.y * rn, v.z * rn, v.w * rn};
    half4v h, l;
    #pragma unroll
    for (int i = 0; i < 4; ++i) {
        _Float16 hh = (_Float16)sv[i];
        h[i] = hh;
        l[i] = (_Float16)(sv[i] - (float)hh);
    }
    *(half4v*)(dhi + tc * 4) = h;
    *(half4v*)(dlo + tc * 4) = l;
}

// K4: 256x256 tile, 8 waves (2 support-halves x 4 query-cols), wave tile 128x64.
// BK=32, dbuf LDS, counted-vmcnt schedule (T3/T4) + setprio (T5). 3-term fp16 split.
__launch_bounds__(512, 2)
__global__ void k_main(const _Float16* __restrict__ shi, const _Float16* __restrict__ slo,
                       const _Float16* __restrict__ qhi, const _Float16* __restrict__ qlo,
                       unsigned long long* __restrict__ keys) {
    extern __shared__ char smem[];
    char* lshi = smem + SH_SHI;
    char* lslo = smem + SH_SLO;
    char* lqhi = smem + SH_QHI;
    char* lqlo = smem + SH_QLO;
    unsigned long long* kl = (unsigned long long*)(smem + SH_KL);

    const int tid  = threadIdx.x;
    const int lane = tid & 63;
    const int wv   = tid >> 6;            // 8 waves
    const int q0   = blockIdx.x * 256;
    const int s0   = blockIdx.y * 256;
    const int wr   = wv >> 2;             // support half 0/1
    const int wc   = wv & 3;              // query col 0..3

    if (tid < 256) kl[tid] = 0ull;

    // ---- staging constants (swizzle slot ^= (row>>1)&3, 16B slots) ----
    const int srow = wv * 16 + (lane >> 2);                 // 0..127 (chunk0 row)
    const int sl0  = ((lane & 3) ^ ((lane >> 3) & 3)) * 16; // row-dependent slot swz
    const size_t gA0 = (size_t)(s0 + srow) * 1024 + sl0;    // bytes; chunk1 = +131072
    const size_t gB0 = (size_t)(q0 + srow) * 1024 + sl0;
    const char* pShi = (const char*)shi; const char* pSlo = (const char*)slo;
    const char* pQhi = (const char*)qhi; const char* pQlo = (const char*)qlo;
    const int dst0 = wv * 1024;           // wave-uniform LDS dest (builtin adds lane*16)
    const int dst1 = 8192 + wv * 1024;

    // ---- fragment read bases (same swizzle; verified mapping) ----
    const int l15 = lane & 15;
    const int kg  = lane >> 4;
    const int swz = (kg ^ ((l15 >> 1) & 3)) * 16;
    const int foA = (wr * 128 + l15) * 64 + swz;   // + fa*1024 + p*16384
    const int foB = (wc * 64  + l15) * 64 + swz;   // + fb*1024 + p*16384

    f32x4 acc[8][4] = {};

#define BAR()    asm volatile("s_barrier" ::: "memory")
#define WAITV8() asm volatile("s_waitcnt vmcnt(8)" ::: "memory")
#define WAITV0() asm volatile("s_waitcnt vmcnt(0)" ::: "memory")
#define WAITL()  asm volatile("s_waitcnt lgkmcnt(0)" ::: "memory")

#define STAGE(P, KT) do {                                                   \
        const size_t kb_ = (size_t)(KT) * 64;                               \
        gload16(pShi + gA0 + kb_,          lshi + (P) * 16384 + dst0);      \
        gload16(pShi + gA0 + 131072 + kb_, lshi + (P) * 16384 + dst1);      \
        gload16(pSlo + gA0 + kb_,          lslo + (P) * 16384 + dst0);      \
        gload16(pSlo + gA0 + 131072 + kb_, lslo + (P) * 16384 + dst1);      \
        gload16(pQhi + gB0 + kb_,          lqhi + (P) * 16384 + dst0);      \
        gload16(pQhi + gB0 + 131072 + kb_, lqhi + (P) * 16384 + dst1);      \
        gload16(pQlo + gB0 + kb_,          lqlo + (P) * 16384 + dst0);      \
        gload16(pQlo + gB0 + 131072 + kb_, lqlo + (P) * 16384 + dst1);      \
    } while (0)

#define RD_A(P, QA) do { _Pragma("unroll")                                  \
        for (int i_ = 0; i_ < 4; ++i_) {                                    \
            ah[i_] = *(const half8v*)(lshi + (P)*16384 + foA + ((QA)*4 + i_)*1024); \
            al[i_] = *(const half8v*)(lslo + (P)*16384 + foA + ((QA)*4 + i_)*1024); \
        } } while (0)

#define RD_B(P, QB) do { _Pragma("unroll")                                  \
        for (int j_ = 0; j_ < 2; ++j_) {                                    \
            bh[j_] = *(const half8v*)(lqhi + (P)*16384 + foB + ((QB)*2 + j_)*1024); \
            bl[j_] = *(const half8v*)(lqlo + (P)*16384 + foB + ((QB)*2 + j_)*1024); \
        } } while (0)

#define MMA(QA, QB) do {                                                    \
        __builtin_amdgcn_s_setprio(1);                                      \
        _Pragma("unroll")                                                   \
        for (int i_ = 0; i_ < 4; ++i_)                                      \
        { _Pragma("unroll")                                                 \
          for (int j_ = 0; j_ < 2; ++j_) {                                  \
            f32x4* a_ = &acc[(QA)*4 + i_][(QB)*2 + j_];                     \
            *a_ = __builtin_amdgcn_mfma_f32_16x16x32_f16(ah[i_], bh[j_], *a_, 0, 0, 0); \
            *a_ = __builtin_amdgcn_mfma_f32_16x16x32_f16(ah[i_], bl[j_], *a_, 0, 0, 0); \
            *a_ = __builtin_amdgcn_mfma_f32_16x16x32_f16(al[i_], bh[j_], *a_, 0, 0, 0); \
          } }                                                               \
        __builtin_amdgcn_s_setprio(0);                                      \
        __builtin_amdgcn_sched_barrier(0);                                  \
    } while (0)

#define COMPUTE_TILE(P) do {                                                \
        half8v ah[4], al[4], bh[2], bl[2];                                  \
        RD_A(P, 0); RD_B(P, 0); MMA(0, 0);                                  \
        RD_B(P, 1);             MMA(0, 1);                                  \
        RD_A(P, 1); RD_B(P, 0); MMA(1, 0);                                  \
        RD_B(P, 1);             MMA(1, 1);                                  \
    } while (0)

// one tile: compute, close reads, refill this buffer (t+2), certify next tile landed
#define HALF(P, TT) do {                                                    \
        COMPUTE_TILE(P);                                                    \
        WAITL(); BAR();                      /* all waves done reading P */ \
        if ((TT) + 2 < 16) { STAGE(P, (TT) + 2); WAITV8(); }                \
        else               { WAITV0(); }                                    \
        BAR();                               /* tile TT+1 landed for all */ \
    } while (0)

    // prologue: tiles 0 and 1 in flight; certify tile 0
    STAGE(0, 0);
    STAGE(1, 1);
    WAITV8();
    BAR();

    for (int t = 0; t < 16; t += 2) {
        HALF(0, t);
        HALF(1, t + 1);
    }

#undef HALF
#undef COMPUTE_TILE
#undef MMA
#undef RD_B
#undef RD_A
#undef STAGE

    // ---- fused argmax epilogue (verified mapping) ----
    // col(query) = wc*64 + fb*16 + l15 ; row(support) = wr*128 + fa*16 + kg*4 + r
    #pragma unroll
    for (int fb = 0; fb < 4; ++fb) {
        unsigned long long best = 0ull;
        #pragma unroll
        for (int fa = 0; fa < 8; ++fa)
            #pragma unroll
            for (int r = 0; r < 4; ++r) {
                const int s = s0 + wr * 128 + fa * 16 + kg * 4 + r;
                if (s < NSUP) {
                    unsigned long long k = pack_key(acc[fa][fb][r], s);
                    if (k > best) best = k;
                }
            }
        unsigned long long o = __shfl_xor(best, 16, 64); if (o > best) best = o;
        o = __shfl_xor(best, 32, 64);                    if (o > best) best = o;
        if (kg == 0) atomicMax(&kl[wc * 64 + fb * 16 + l15], best);
    }
    __syncthreads();
    if (tid < 256) {
        const int q = q0 + tid;
        if (q < NQRY && kl[tid] != 0ull) atomicMax(&keys[q], kl[tid]);
    }
}

// K5: decode packed key -> class index
__global__ void k_decode(const unsigned long long* __restrict__ keys, int* __restrict__ out) {
    const int q = blockIdx.x * 256 + threadIdx.x;
    if (q < NQRY) {
        unsigned sidx = 0xFFFFFFFFu - (unsigned)(keys[q] & 0xFFFFFFFFull);
        out[q] = (int)(sidx / 5u);
    }
}

extern "C" void kernel_launch(void* const* d_in, const int* in_sizes, int n_in,
                              void* d_out, int out_size, void* d_ws, size_t ws_size,
                              hipStream_t stream) {
    const float* sup = (const float*)d_in[0];   // [1000,5,512]
    const float* qry = (const float*)d_in[1];   // [5000,512]
    // d_in[2] = use_cosine: after normalization argmin-euclid == argmax-cosine.
    int* out = (int*)d_out;

    char* ws = (char*)d_ws;
    _Float16* shi = (_Float16*)(ws + OFF_SHI);
    _Float16* slo = (_Float16*)(ws + OFF_SLO);
    _Float16* qhi = (_Float16*)(ws + OFF_QHI);
    _Float16* qlo = (_Float16*)(ws + OFF_QLO);
    float* partial = (float*)(ws + OFF_PARTIAL);
    float* mean    = (float*)(ws + OFF_MEAN);
    unsigned long long* keys = (unsigned long long*)(ws + OFF_KEYS);

    // allow 130KB dynamic LDS (idempotent; not a stream op, capture-safe)
    static bool attr_set = false;
    if (!attr_set) {
        (void)hipFuncSetAttribute((const void*)k_main,
                                  hipFuncAttributeMaxDynamicSharedMemorySize, SH_TOTAL);
        attr_set = true;
    }

    k_partial_mean<<<MEAN_BLOCKS, 512, 0, stream>>>(sup, partial);
    k_mean_init<<<1, 512, 0, stream>>>(partial, mean, keys);
    k_split<<<(2 * NPAD) / 4, 512, 0, stream>>>(sup, qry, mean, shi, slo, qhi, qlo);
    dim3 grid(NPAD / 256, NPAD / 256);
    k_main<<<grid, 512, SH_TOTAL, stream>>>(shi, slo, qhi, qlo, keys);
    k_decode<<<(NQRY + 255) / 256, 256, 0, stream>>>(keys, out);
}

// Round 5
// 165.671 us; speedup vs baseline: 1.1115x; 1.0548x over previous
//
#include <hip/hip_runtime.h>
#include <stdint.h>

#define D     512
#define NSUP  5000   // 1000 classes * 5 shots
#define NQRY  5000
#define NPAD  5120   // 20 tiles of 256
#define MEAN_BLOCKS 100
#define ROWS_PER_MEAN_BLOCK 50
#define SCALE 512.0f

// ---------------- ws layout (bytes, unchanged) ----------------
#define OFF_SHI     0
#define OFF_SLO     5242880
#define OFF_QHI     10485760
#define OFF_QLO     15728640
#define OFF_PARTIAL 20971520
#define OFF_MEAN    21176320
#define OFF_KEYS    21178368

// ---------------- dynamic LDS layout (bytes) ----------------
#define SH_SHI   0
#define SH_SLO   32768
#define SH_QHI   65536
#define SH_QLO   98304
#define SH_KL    131072
#define SH_TOTAL (131072 + 2048)

typedef _Float16 half4v __attribute__((ext_vector_type(4)));
typedef _Float16 half8v __attribute__((ext_vector_type(8)));
typedef float    f32x4  __attribute__((ext_vector_type(4)));

__device__ __forceinline__ unsigned long long pack_key(float v, int sidx) {
    unsigned u = __float_as_uint(v);
    u = (u & 0x80000000u) ? ~u : (u | 0x80000000u);   // monotone float->uint
    return ((unsigned long long)u << 32) | (unsigned)(0xFFFFFFFFu - (unsigned)sidx);
}

__device__ __forceinline__ void gload16(const void* g, void* l) {
    __builtin_amdgcn_global_load_lds(
        (const __attribute__((address_space(1))) unsigned int*)g,
        (__attribute__((address_space(3))) unsigned int*)l, 16, 0, 0);
}

// K1: partial column sums of support rows (deterministic 2-stage mean)
__global__ void k_partial_mean(const float* __restrict__ sup, float* __restrict__ partial) {
    const int col = threadIdx.x;           // 512
    const int b   = blockIdx.x;            // 100
    const int r0  = b * ROWS_PER_MEAN_BLOCK;
    float acc = 0.0f;
    #pragma unroll 5
    for (int r = 0; r < ROWS_PER_MEAN_BLOCK; ++r)
        acc += sup[(size_t)(r0 + r) * D + col];
    partial[b * D + col] = acc;
}

// K2: finish mean, zero keys
__global__ void k_mean_init(const float* __restrict__ partial, float* __restrict__ mean,
                            unsigned long long* __restrict__ keys) {
    const int col = threadIdx.x;           // 512
    float acc = 0.0f;
    #pragma unroll 4
    for (int b = 0; b < MEAN_BLOCKS; ++b) acc += partial[b * D + col];
    mean[col] = acc * (1.0f / (float)NSUP);
    for (int i = col; i < NSUP; i += 512) keys[i] = 0ull;
}

// K3: center + L2-normalize + scale by 512 + split into fp16 hi/lo.
__global__ void k_split(const float* __restrict__ sup, const float* __restrict__ qry,
                        const float* __restrict__ mean,
                        _Float16* __restrict__ shi, _Float16* __restrict__ slo,
                        _Float16* __restrict__ qhi, _Float16* __restrict__ qlo) {
    const int t    = threadIdx.x;
    const int rloc = t >> 7;               // row within block, 0..3
    const int tc   = t & 127;              // 128 threads per row
    const int b    = (int)blockIdx.x * 4 + rloc;   // global row id 0..10239
    const float* src; _Float16 *dhi, *dlo; int valid;
    if (b < NPAD) { src = sup + (size_t)b * D;
                    dhi = shi + (size_t)b * D; dlo = slo + (size_t)b * D; valid = (b < NSUP); }
    else          { int r = b - NPAD; src = qry + (size_t)r * D;
                    dhi = qhi + (size_t)r * D; dlo = qlo + (size_t)r * D; valid = (r < NQRY); }
    __shared__ float red[8];
    if (!valid) {
        half4v z = {};
        *(half4v*)(dhi + tc * 4) = z;
        *(half4v*)(dlo + tc * 4) = z;
        return;
    }
    float4 v = *(const float4*)(src + tc * 4);
    float4 m = *(const float4*)(mean + tc * 4);
    v.x -= m.x; v.y -= m.y; v.z -= m.z; v.w -= m.w;
    float ss = v.x * v.x + v.y * v.y + v.z * v.z + v.w * v.w;
    #pragma unroll
    for (int off = 32; off > 0; off >>= 1) ss += __shfl_down(ss, off, 64);
    if ((t & 63) == 0) red[t >> 6] = ss;
    __syncthreads();
    const float rn = SCALE / sqrtf(red[rloc * 2] + red[rloc * 2 + 1]);
    float sv[4] = {v.x * rn, v.y * rn, v.z * rn, v.w * rn};
    half4v h, l;
    #pragma unroll
    for (int i = 0; i < 4; ++i) {
        _Float16 hh = (_Float16)sv[i];
        h[i] = hh;
        l[i] = (_Float16)(sv[i] - (float)hh);
    }
    *(half4v*)(dhi + tc * 4) = h;
    *(half4v*)(dlo + tc * 4) = l;
}

// K4: 256x256 tile, 8 waves, wave tile 128x64, BK=32, dbuf LDS.
// m201-style 4-phase/K-tile interleave: {ds_read quad || stage t+1 || BAR ||
// lgkmcnt(0) || prio1 24-MFMA prio0 || BAR}, vmcnt(0) only at tile boundary
// (early-issued loads have 1-4 MFMA clusters of cover). 3-term fp16 split.
__launch_bounds__(512, 2)
__global__ void k_main(const _Float16* __restrict__ shi, const _Float16* __restrict__ slo,
                       const _Float16* __restrict__ qhi, const _Float16* __restrict__ qlo,
                       unsigned long long* __restrict__ keys) {
    extern __shared__ char smem[];
    char* lshi = smem + SH_SHI;
    char* lslo = smem + SH_SLO;
    char* lqhi = smem + SH_QHI;
    char* lqlo = smem + SH_QLO;
    unsigned long long* kl = (unsigned long long*)(smem + SH_KL);

    const int tid  = threadIdx.x;
    const int lane = tid & 63;
    const int wv   = tid >> 6;            // 8 waves
    const int q0   = blockIdx.x * 256;
    const int s0   = blockIdx.y * 256;
    const int wr   = wv >> 2;             // support half 0/1
    const int wc   = wv & 3;              // query col 0..3

    if (tid < 256) kl[tid] = 0ull;

    // ---- staging addresses (verified in R4; swizzle slot ^= row-bits, 16B slots) ----
    const int srow = wv * 16 + (lane >> 2);                 // chunk0 row 0..127
    const int sl0  = ((lane & 3) ^ ((lane >> 3) & 3)) * 16;
    const size_t gA0 = (size_t)(s0 + srow) * 1024 + sl0;    // +131072 -> rows 128..255
    const size_t gB0 = (size_t)(q0 + srow) * 1024 + sl0;
    const char* pShi = (const char*)shi; const char* pSlo = (const char*)slo;
    const char* pQhi = (const char*)qhi; const char* pQlo = (const char*)qlo;
    const int dst0 = wv * 1024;           // wave-uniform LDS dest (+lane*16 by HW)
    const int dst1 = 8192 + wv * 1024;

    // ---- fragment read bases (verified in R4) ----
    const int l15 = lane & 15;
    const int kg  = lane >> 4;
    const int swz = (kg ^ ((l15 >> 1) & 3)) * 16;
    const int foA = (wr * 128 + l15) * 64 + swz;   // + (QA*4+i)*1024 + P*16384
    const int foB = (wc * 64  + l15) * 64 + swz;   // + (QB*2+j)*1024 + P*16384

    f32x4 acc[8][4] = {};

#define BAR()    asm volatile("s_barrier" ::: "memory")
#define WAITV0() asm volatile("s_waitcnt vmcnt(0)" ::: "memory")
#define WAITL()  asm volatile("s_waitcnt lgkmcnt(0)" ::: "memory")

// stage of one K-tile = 8 gload16 calls, split 3/3/2 across phases 1-3
#define STAGE_A(P, KT) do { const size_t kb_ = (size_t)(KT) * 64;           \
        gload16(pShi + gA0 + kb_,          lshi + (P) * 16384 + dst0);      \
        gload16(pShi + gA0 + 131072 + kb_, lshi + (P) * 16384 + dst1);      \
        gload16(pSlo + gA0 + kb_,          lslo + (P) * 16384 + dst0);      \
    } while (0)
#define STAGE_B(P, KT) do { const size_t kb_ = (size_t)(KT) * 64;           \
        gload16(pSlo + gA0 + 131072 + kb_, lslo + (P) * 16384 + dst1);      \
        gload16(pQhi + gB0 + kb_,          lqhi + (P) * 16384 + dst0);      \
        gload16(pQhi + gB0 + 131072 + kb_, lqhi + (P) * 16384 + dst1);      \
    } while (0)
#define STAGE_C(P, KT) do { const size_t kb_ = (size_t)(KT) * 64;           \
        gload16(pQlo + gB0 + kb_,          lqlo + (P) * 16384 + dst0);      \
        gload16(pQlo + gB0 + 131072 + kb_, lqlo + (P) * 16384 + dst1);      \
    } while (0)

#define RD_A(P, QA) do { _Pragma("unroll")                                  \
        for (int i_ = 0; i_ < 4; ++i_) {                                    \
            ah[i_] = *(const half8v*)(lshi + (P)*16384 + foA + ((QA)*4 + i_)*1024); \
            al[i_] = *(const half8v*)(lslo + (P)*16384 + foA + ((QA)*4 + i_)*1024); \
        } } while (0)

#define RD_B(P, QB, BH, BL) do { _Pragma("unroll")                          \
        for (int j_ = 0; j_ < 2; ++j_) {                                    \
            BH[j_] = *(const half8v*)(lqhi + (P)*16384 + foB + ((QB)*2 + j_)*1024); \
            BL[j_] = *(const half8v*)(lqlo + (P)*16384 + foB + ((QB)*2 + j_)*1024); \
        } } while (0)

#define MMA_Q(QA, QB, BH, BL) do {                                          \
        __builtin_amdgcn_s_setprio(1);                                      \
        _Pragma("unroll")                                                   \
        for (int i_ = 0; i_ < 4; ++i_)                                      \
        { _Pragma("unroll")                                                 \
          for (int j_ = 0; j_ < 2; ++j_) {                                  \
            f32x4* a_ = &acc[(QA)*4 + i_][(QB)*2 + j_];                     \
            *a_ = __builtin_amdgcn_mfma_f32_16x16x32_f16(ah[i_], BH[j_], *a_, 0, 0, 0); \
            *a_ = __builtin_amdgcn_mfma_f32_16x16x32_f16(ah[i_], BL[j_], *a_, 0, 0, 0); \
            *a_ = __builtin_amdgcn_mfma_f32_16x16x32_f16(al[i_], BH[j_], *a_, 0, 0, 0); \
          } }                                                               \
        __builtin_amdgcn_s_setprio(0);                                      \
        __builtin_amdgcn_sched_barrier(0);                                  \
    } while (0)

    // prologue: stage tile 0 only, certify it
    STAGE_A(0, 0); STAGE_B(0, 0); STAGE_C(0, 0);
    WAITV0();
    BAR();

    for (int t = 0; t < 16; ++t) {
        const int P    = t & 1;
        const int Pn   = P ^ 1;
        const int n    = t + 1;
        const bool more = (n < 16);
        half8v ah[4], al[4], bh0[2], bl0[2], bh1[2], bl1[2];

        // phase 1: quadrant (0,0)
        RD_A(P, 0);
        RD_B(P, 0, bh0, bl0);
        if (more) STAGE_A(Pn, n);
        BAR(); WAITL();
        MMA_Q(0, 0, bh0, bl0);
        BAR();

        // phase 2: quadrant (0,1)
        RD_B(P, 1, bh1, bl1);
        if (more) STAGE_B(Pn, n);
        BAR(); WAITL();
        MMA_Q(0, 1, bh1, bl1);
        BAR();

        // phase 3: quadrant (1,0) — reuses bh0/bl0
        RD_A(P, 1);
        if (more) STAGE_C(Pn, n);
        BAR(); WAITL();
        MMA_Q(1, 0, bh0, bl0);
        BAR();

        // phase 4: quadrant (1,1) — reuses bh1/bl1; then tile boundary
        MMA_Q(1, 1, bh1, bl1);
        WAITV0();                       // t+1's 8 loads: issued 1-4 clusters ago
        BAR();
    }

#undef MMA_Q
#undef RD_B
#undef RD_A
#undef STAGE_C
#undef STAGE_B
#undef STAGE_A

    // ---- fused argmax epilogue (verified mapping) ----
    // col(query) = wc*64 + fb*16 + l15 ; row(support) = wr*128 + fa*16 + kg*4 + r
    #pragma unroll
    for (int fb = 0; fb < 4; ++fb) {
        unsigned long long best = 0ull;
        #pragma unroll
        for (int fa = 0; fa < 8; ++fa)
            #pragma unroll
            for (int r = 0; r < 4; ++r) {
                const int s = s0 + wr * 128 + fa * 16 + kg * 4 + r;
                if (s < NSUP) {
                    unsigned long long k = pack_key(acc[fa][fb][r], s);
                    if (k > best) best = k;
                }
            }
        unsigned long long o = __shfl_xor(best, 16, 64); if (o > best) best = o;
        o = __shfl_xor(best, 32, 64);                    if (o > best) best = o;
        if (kg == 0) atomicMax(&kl[wc * 64 + fb * 16 + l15], best);
    }
    __syncthreads();
    if (tid < 256) {
        const int q = q0 + tid;
        if (q < NQRY && kl[tid] != 0ull) atomicMax(&keys[q], kl[tid]);
    }
}

// K5: decode packed key -> class index
__global__ void k_decode(const unsigned long long* __restrict__ keys, int* __restrict__ out) {
    const int q = blockIdx.x * 256 + threadIdx.x;
    if (q < NQRY) {
        unsigned sidx = 0xFFFFFFFFu - (unsigned)(keys[q] & 0xFFFFFFFFull);
        out[q] = (int)(sidx / 5u);
    }
}

extern "C" void kernel_launch(void* const* d_in, const int* in_sizes, int n_in,
                              void* d_out, int out_size, void* d_ws, size_t ws_size,
                              hipStream_t stream) {
    const float* sup = (const float*)d_in[0];   // [1000,5,512]
    const float* qry = (const float*)d_in[1];   // [5000,512]
    // d_in[2] = use_cosine: after normalization argmin-euclid == argmax-cosine.
    int* out = (int*)d_out;

    char* ws = (char*)d_ws;
    _Float16* shi = (_Float16*)(ws + OFF_SHI);
    _Float16* slo = (_Float16*)(ws + OFF_SLO);
    _Float16* qhi = (_Float16*)(ws + OFF_QHI);
    _Float16* qlo = (_Float16*)(ws + OFF_QLO);
    float* partial = (float*)(ws + OFF_PARTIAL);
    float* mean    = (float*)(ws + OFF_MEAN);
    unsigned long long* keys = (unsigned long long*)(ws + OFF_KEYS);

    // allow 130KB dynamic LDS (idempotent; not a stream op, capture-safe)
    static bool attr_set = false;
    if (!attr_set) {
        (void)hipFuncSetAttribute((const void*)k_main,
                                  hipFuncAttributeMaxDynamicSharedMemorySize, SH_TOTAL);
        attr_set = true;
    }

    k_partial_mean<<<MEAN_BLOCKS, 512, 0, stream>>>(sup, partial);
    k_mean_init<<<1, 512, 0, stream>>>(partial, mean, keys);
    k_split<<<(2 * NPAD) / 4, 512, 0, stream>>>(sup, qry, mean, shi, slo, qhi, qlo);
    dim3 grid(NPAD / 256, NPAD / 256);
    k_main<<<grid, 512, SH_TOTAL, stream>>>(shi, slo, qhi, qlo, keys);
    k_decode<<<(NQRY + 255) / 256, 256, 0, stream>>>(keys, out);
}

// Round 6
// 165.444 us; speedup vs baseline: 1.1130x; 1.0014x over previous
//
#include <hip/hip_runtime.h>
#include <stdint.h>

#define D     512
#define NSUP  5000   // 1000 classes * 5 shots
#define NQRY  5000
#define NPAD  5120   // 20 tiles of 256
#define MEAN_BLOCKS 100
#define ROWS_PER_MEAN_BLOCK 50
#define SCALE 512.0f

// ---------------- ws layout (bytes, unchanged) ----------------
#define OFF_SHI     0
#define OFF_SLO     5242880
#define OFF_QHI     10485760
#define OFF_QLO     15728640
#define OFF_PARTIAL 20971520
#define OFF_MEAN    21176320
#define OFF_KEYS    21178368

// ---------------- dynamic LDS layout (bytes) ----------------
#define SH_SHI   0
#define SH_SLO   32768
#define SH_QHI   65536
#define SH_QLO   98304
#define SH_KL    131072
#define SH_TOTAL (131072 + 2048)

typedef _Float16 half4v __attribute__((ext_vector_type(4)));
typedef _Float16 half8v __attribute__((ext_vector_type(8)));
typedef float    f32x4  __attribute__((ext_vector_type(4)));

__device__ __forceinline__ unsigned long long pack_key(float v, int sidx) {
    unsigned u = __float_as_uint(v);
    u = (u & 0x80000000u) ? ~u : (u | 0x80000000u);   // monotone float->uint
    return ((unsigned long long)u << 32) | (unsigned)(0xFFFFFFFFu - (unsigned)sidx);
}

__device__ __forceinline__ void gload16(const void* g, void* l) {
    __builtin_amdgcn_global_load_lds(
        (const __attribute__((address_space(1))) unsigned int*)g,
        (__attribute__((address_space(3))) unsigned int*)l, 16, 0, 0);
}

// K1: partial column sums of support rows (deterministic 2-stage mean)
__global__ void k_partial_mean(const float* __restrict__ sup, float* __restrict__ partial) {
    const int col = threadIdx.x;           // 512
    const int b   = blockIdx.x;            // 100
    const int r0  = b * ROWS_PER_MEAN_BLOCK;
    float acc = 0.0f;
    #pragma unroll 5
    for (int r = 0; r < ROWS_PER_MEAN_BLOCK; ++r)
        acc += sup[(size_t)(r0 + r) * D + col];
    partial[b * D + col] = acc;
}

// K2: finish mean, zero keys
__global__ void k_mean_init(const float* __restrict__ partial, float* __restrict__ mean,
                            unsigned long long* __restrict__ keys) {
    const int col = threadIdx.x;           // 512
    float acc = 0.0f;
    #pragma unroll 4
    for (int b = 0; b < MEAN_BLOCKS; ++b) acc += partial[b * D + col];
    mean[col] = acc * (1.0f / (float)NSUP);
    for (int i = col; i < NSUP; i += 512) keys[i] = 0ull;
}

// K3: center + L2-normalize + scale by 512 + split into fp16 hi/lo.
__global__ void k_split(const float* __restrict__ sup, const float* __restrict__ qry,
                        const float* __restrict__ mean,
                        _Float16* __restrict__ shi, _Float16* __restrict__ slo,
                        _Float16* __restrict__ qhi, _Float16* __restrict__ qlo) {
    const int t    = threadIdx.x;
    const int rloc = t >> 7;               // row within block, 0..3
    const int tc   = t & 127;              // 128 threads per row
    const int b    = (int)blockIdx.x * 4 + rloc;   // global row id 0..10239
    const float* src; _Float16 *dhi, *dlo; int valid;
    if (b < NPAD) { src = sup + (size_t)b * D;
                    dhi = shi + (size_t)b * D; dlo = slo + (size_t)b * D; valid = (b < NSUP); }
    else          { int r = b - NPAD; src = qry + (size_t)r * D;
                    dhi = qhi + (size_t)r * D; dlo = qlo + (size_t)r * D; valid = (r < NQRY); }
    __shared__ float red[8];
    if (!valid) {
        half4v z = {};
        *(half4v*)(dhi + tc * 4) = z;
        *(half4v*)(dlo + tc * 4) = z;
        return;
    }
    float4 v = *(const float4*)(src + tc * 4);
    float4 m = *(const float4*)(mean + tc * 4);
    v.x -= m.x; v.y -= m.y; v.z -= m.z; v.w -= m.w;
    float ss = v.x * v.x + v.y * v.y + v.z * v.z + v.w * v.w;
    #pragma unroll
    for (int off = 32; off > 0; off >>= 1) ss += __shfl_down(ss, off, 64);
    if ((t & 63) == 0) red[t >> 6] = ss;
    __syncthreads();
    const float rn = SCALE / sqrtf(red[rloc * 2] + red[rloc * 2 + 1]);
    float sv[4] = {v.x * rn, v.y * rn, v.z * rn, v.w * rn};
    half4v h, l;
    #pragma unroll
    for (int i = 0; i < 4; ++i) {
        _Float16 hh = (_Float16)sv[i];
        h[i] = hh;
        l[i] = (_Float16)(sv[i] - (float)hh);
    }
    *(half4v*)(dhi + tc * 4) = h;
    *(half4v*)(dlo + tc * 4) = l;
}

// K4: 256x256 tile, 8 waves, wave tile 128x64, BK=32, dbuf LDS.
// 8 balanced phases per K-tile (12 MFMA each): {ds_reads || 2 stage-gloads ||
// BAR || lgkmcnt(0) || prio1 12-MFMA prio0 || BAR}. All 8 next-tile gloads in
// flight by phase 3 -> cheap vmcnt(0) at tile boundary. 3-term fp16 split.
__launch_bounds__(512, 2)
__global__ void k_main(const _Float16* __restrict__ shi, const _Float16* __restrict__ slo,
                       const _Float16* __restrict__ qhi, const _Float16* __restrict__ qlo,
                       unsigned long long* __restrict__ keys) {
    extern __shared__ char smem[];
    char* lshi = smem + SH_SHI;
    char* lslo = smem + SH_SLO;
    char* lqhi = smem + SH_QHI;
    char* lqlo = smem + SH_QLO;
    unsigned long long* kl = (unsigned long long*)(smem + SH_KL);

    const int tid  = threadIdx.x;
    const int lane = tid & 63;
    const int wv   = tid >> 6;            // 8 waves
    const int q0   = blockIdx.x * 256;
    const int s0   = blockIdx.y * 256;
    const int wr   = wv >> 2;             // support half 0/1
    const int wc   = wv & 3;              // query col 0..3

    if (tid < 256) kl[tid] = 0ull;

    // ---- staging addresses (verified R4/R5; swizzle slot ^= row-bits, 16B slots) ----
    const int srow = wv * 16 + (lane >> 2);                 // chunk0 row 0..127
    const int sl0  = ((lane & 3) ^ ((lane >> 3) & 3)) * 16;
    const size_t gA0 = (size_t)(s0 + srow) * 1024 + sl0;    // +131072 -> rows 128..255
    const size_t gB0 = (size_t)(q0 + srow) * 1024 + sl0;
    const char* pShi = (const char*)shi; const char* pSlo = (const char*)slo;
    const char* pQhi = (const char*)qhi; const char* pQlo = (const char*)qlo;
    const int dst0 = wv * 1024;           // wave-uniform LDS dest (+lane*16 by HW)
    const int dst1 = 8192 + wv * 1024;

    // ---- fragment read bases (verified R4/R5) ----
    const int l15 = lane & 15;
    const int kg  = lane >> 4;
    const int swz = (kg ^ ((l15 >> 1) & 3)) * 16;
    const int foA = (wr * 128 + l15) * 64 + swz;   // + fa*1024 + P*16384
    const int foB = (wc * 64  + l15) * 64 + swz;   // + fb*1024 + P*16384

    f32x4 acc[8][4] = {};

#define BAR()    asm volatile("s_barrier" ::: "memory")
#define WAITV0() asm volatile("s_waitcnt vmcnt(0)" ::: "memory")
#define WAITL()  asm volatile("s_waitcnt lgkmcnt(0)" ::: "memory")

// stage pair k (k=0..3) of tile KT into buffer P: 2 gload16 lines
#define ST2(P, KT, K2) do { const size_t kb_ = (size_t)(KT) * 64;           \
        if ((K2) == 0) {                                                    \
            gload16(pShi + gA0 + kb_,          lshi + (P) * 16384 + dst0);  \
            gload16(pShi + gA0 + 131072 + kb_, lshi + (P) * 16384 + dst1);  \
        } else if ((K2) == 1) {                                             \
            gload16(pSlo + gA0 + kb_,          lslo + (P) * 16384 + dst0);  \
            gload16(pSlo + gA0 + 131072 + kb_, lslo + (P) * 16384 + dst1);  \
        } else if ((K2) == 2) {                                             \
            gload16(pQhi + gB0 + kb_,          lqhi + (P) * 16384 + dst0);  \
            gload16(pQhi + gB0 + 131072 + kb_, lqhi + (P) * 16384 + dst1);  \
        } else {                                                            \
            gload16(pQlo + gB0 + kb_,          lqlo + (P) * 16384 + dst0);  \
            gload16(pQlo + gB0 + 131072 + kb_, lqlo + (P) * 16384 + dst1);  \
        } } while (0)

// read 2 A-fragments (global frag ids FA, FA+1) into ah/al slots AI, AI+1
#define RD_A2(P, FA, AI) do {                                               \
        ah[AI]   = *(const half8v*)(lshi + (P)*16384 + foA + (FA)*1024);    \
        al[AI]   = *(const half8v*)(lslo + (P)*16384 + foA + (FA)*1024);    \
        ah[AI+1] = *(const half8v*)(lshi + (P)*16384 + foA + (FA+1)*1024);  \
        al[AI+1] = *(const half8v*)(lslo + (P)*16384 + foA + (FA+1)*1024);  \
    } while (0)

#define RD_B(P, QB, BH, BL) do { _Pragma("unroll")                          \
        for (int j_ = 0; j_ < 2; ++j_) {                                    \
            BH[j_] = *(const half8v*)(lqhi + (P)*16384 + foB + ((QB)*2 + j_)*1024); \
            BL[j_] = *(const half8v*)(lqlo + (P)*16384 + foB + ((QB)*2 + j_)*1024); \
        } } while (0)

// 12 MFMA: acc rows R0,R0+1 (ah/al slots AI,AI+1) x acc cols C0,C0+1
#define MMA12(R0, AI, C0, BH, BL) do {                                      \
        __builtin_amdgcn_s_setprio(1);                                      \
        _Pragma("unroll")                                                   \
        for (int i_ = 0; i_ < 2; ++i_)                                      \
        { _Pragma("unroll")                                                 \
          for (int j_ = 0; j_ < 2; ++j_) {                                  \
            f32x4* a_ = &acc[(R0) + i_][(C0) + j_];                         \
            *a_ = __builtin_amdgcn_mfma_f32_16x16x32_f16(ah[(AI)+i_], BH[j_], *a_, 0, 0, 0); \
            *a_ = __builtin_amdgcn_mfma_f32_16x16x32_f16(ah[(AI)+i_], BL[j_], *a_, 0, 0, 0); \
            *a_ = __builtin_amdgcn_mfma_f32_16x16x32_f16(al[(AI)+i_], BH[j_], *a_, 0, 0, 0); \
          } }                                                               \
        __builtin_amdgcn_s_setprio(0);                                      \
        __builtin_amdgcn_sched_barrier(0);                                  \
    } while (0)

    // prologue: stage tile 0, certify
    ST2(0, 0, 0); ST2(0, 0, 1); ST2(0, 0, 2); ST2(0, 0, 3);
    WAITV0();
    BAR();

    for (int t = 0; t < 16; ++t) {
        const int P  = t & 1;
        const int Pn = P ^ 1;
        const int tn = (t + 1 < 16) ? (t + 1) : 0;   // wrap: harmless in-bounds restage
        half8v ah[4], al[4], bh0[2], bl0[2], bh1[2], bl1[2];

        // ph0: A0 frags 0-1 + B0 reads; stage pair 0
        RD_A2(P, 0, 0); RD_B(P, 0, bh0, bl0); ST2(Pn, tn, 0);
        BAR(); WAITL(); MMA12(0, 0, 0, bh0, bl0); BAR();
        // ph1: A0 frags 2-3; stage pair 1
        RD_A2(P, 2, 2); ST2(Pn, tn, 1);
        BAR(); WAITL(); MMA12(2, 2, 0, bh0, bl0); BAR();
        // ph2: B1 reads; stage pair 2
        RD_B(P, 1, bh1, bl1); ST2(Pn, tn, 2);
        BAR(); WAITL(); MMA12(0, 0, 2, bh1, bl1); BAR();
        // ph3: stage pair 3 (all 8 next-tile loads now in flight)
        ST2(Pn, tn, 3);
        BAR(); MMA12(2, 2, 2, bh1, bl1); BAR();
        // ph4: A1 frags 4-5 (reuse slots 0-1; A0 dead)
        RD_A2(P, 4, 0);
        BAR(); WAITL(); MMA12(4, 0, 0, bh0, bl0); BAR();
        // ph5: A1 frags 6-7
        RD_A2(P, 6, 2);
        BAR(); WAITL(); MMA12(6, 2, 0, bh0, bl0); BAR();
        // ph6
        BAR(); MMA12(4, 0, 2, bh1, bl1); BAR();
        // ph7 + tile boundary (loads have had ~4 phases of cover)
        BAR(); MMA12(6, 2, 2, bh1, bl1);
        WAITV0();
        BAR();
    }

#undef MMA12
#undef RD_B
#undef RD_A2
#undef ST2

    // ---- fused argmax epilogue (verified mapping) ----
    // col(query) = wc*64 + fb*16 + l15 ; row(support) = wr*128 + fa*16 + kg*4 + r
    #pragma unroll
    for (int fb = 0; fb < 4; ++fb) {
        unsigned long long best = 0ull;
        #pragma unroll
        for (int fa = 0; fa < 8; ++fa)
            #pragma unroll
            for (int r = 0; r < 4; ++r) {
                const int s = s0 + wr * 128 + fa * 16 + kg * 4 + r;
                if (s < NSUP) {
                    unsigned long long k = pack_key(acc[fa][fb][r], s);
                    if (k > best) best = k;
                }
            }
        unsigned long long o = __shfl_xor(best, 16, 64); if (o > best) best = o;
        o = __shfl_xor(best, 32, 64);                    if (o > best) best = o;
        if (kg == 0) atomicMax(&kl[wc * 64 + fb * 16 + l15], best);
    }
    __syncthreads();
    if (tid < 256) {
        const int q = q0 + tid;
        if (q < NQRY && kl[tid] != 0ull) atomicMax(&keys[q], kl[tid]);
    }
}

// K5: decode packed key -> class index
__global__ void k_decode(const unsigned long long* __restrict__ keys, int* __restrict__ out) {
    const int q = blockIdx.x * 256 + threadIdx.x;
    if (q < NQRY) {
        unsigned sidx = 0xFFFFFFFFu - (unsigned)(keys[q] & 0xFFFFFFFFull);
        out[q] = (int)(sidx / 5u);
    }
}

extern "C" void kernel_launch(void* const* d_in, const int* in_sizes, int n_in,
                              void* d_out, int out_size, void* d_ws, size_t ws_size,
                              hipStream_t stream) {
    const float* sup = (const float*)d_in[0];   // [1000,5,512]
    const float* qry = (const float*)d_in[1];   // [5000,512]
    // d_in[2] = use_cosine: after normalization argmin-euclid == argmax-cosine.
    int* out = (int*)d_out;

    char* ws = (char*)d_ws;
    _Float16* shi = (_Float16*)(ws + OFF_SHI);
    _Float16* slo = (_Float16*)(ws + OFF_SLO);
    _Float16* qhi = (_Float16*)(ws + OFF_QHI);
    _Float16* qlo = (_Float16*)(ws + OFF_QLO);
    float* partial = (float*)(ws + OFF_PARTIAL);
    float* mean    = (float*)(ws + OFF_MEAN);
    unsigned long long* keys = (unsigned long long*)(ws + OFF_KEYS);

    // allow 130KB dynamic LDS (idempotent; not a stream op, capture-safe)
    static bool attr_set = false;
    if (!attr_set) {
        (void)hipFuncSetAttribute((const void*)k_main,
                                  hipFuncAttributeMaxDynamicSharedMemorySize, SH_TOTAL);
        attr_set = true;
    }

    k_partial_mean<<<MEAN_BLOCKS, 512, 0, stream>>>(sup, partial);
    k_mean_init<<<1, 512, 0, stream>>>(partial, mean, keys);
    k_split<<<(2 * NPAD) / 4, 512, 0, stream>>>(sup, qry, mean, shi, slo, qhi, qlo);
    dim3 grid(NPAD / 256, NPAD / 256);
    k_main<<<grid, 512, SH_TOTAL, stream>>>(shi, slo, qhi, qlo, keys);
    k_decode<<<(NQRY + 255) / 256, 256, 0, stream>>>(keys, out);
}